// Round 3
// baseline (4516.613 us; speedup 1.0000x reference)
//
#include <hip/hip_runtime.h>
#include <math.h>

#define B_    8
#define N_    96
#define EMB_  768
#define HID_  384
#define GID_  1152   // 3*HID
#define CONC_ 1152   // (L+1)*HID
#define CODE_ 192
#define FEAT_ 768

__device__ __forceinline__ float sigf(float x) { return 1.0f / (1.0f + expf(-x)); }

// LLC-coherent (agent-scope) relaxed atomic accessors (proven visibility path).
__device__ __forceinline__ void atstf(float* p, float v) {
  __hip_atomic_store(p, v, __ATOMIC_RELAXED, __HIP_MEMORY_SCOPE_AGENT);
}
__device__ __forceinline__ float atldf(const float* p) {
  return __hip_atomic_load((float*)p, __ATOMIC_RELAXED, __HIP_MEMORY_SCOPE_AGENT);
}
// Spin until the element leaves its sentinel state (0xFFFFFFFF via memset 0xFF;
// a negative all-ones-payload NaN cannot be produced by IEEE arithmetic).
__device__ __forceinline__ float spinld(const float* p) {
  float f = atldf(p);
  while (__float_as_uint(f) == 0xFFFFFFFFu) f = atldf(p);
  return f;
}

// ---------------- generic GEMM: C[M,N] = act(A @ W^T + bias) ----------------
template<int RELU>
__global__ __launch_bounds__(256)
void gemm_bias(const float* __restrict__ A, int lda,
               const float* __restrict__ W,
               const float* __restrict__ bias,
               float* __restrict__ C, int ldc, int K)
{
  __shared__ float As[16][68];
  __shared__ float Bs[16][68];
  const int tid = threadIdx.x;
  const int m0 = blockIdx.y * 64;
  const int n0 = blockIdx.x * 64;
  const int lr = tid >> 2;
  const int lc = (tid & 3) * 4;
  const int ty = tid >> 4, tx = tid & 15;
  float acc[4][4] = {};
  for (int k0 = 0; k0 < K; k0 += 16) {
    float4 a4 = *(const float4*)(A + (size_t)(m0 + lr) * lda + k0 + lc);
    float4 b4 = *(const float4*)(W + (size_t)(n0 + lr) * K + k0 + lc);
    As[lc+0][lr] = a4.x; As[lc+1][lr] = a4.y; As[lc+2][lr] = a4.z; As[lc+3][lr] = a4.w;
    Bs[lc+0][lr] = b4.x; Bs[lc+1][lr] = b4.y; Bs[lc+2][lr] = b4.z; Bs[lc+3][lr] = b4.w;
    __syncthreads();
#pragma unroll
    for (int k = 0; k < 16; ++k) {
      float av[4], bv[4];
#pragma unroll
      for (int i = 0; i < 4; ++i) av[i] = As[k][ty*4+i];
#pragma unroll
      for (int j = 0; j < 4; ++j) bv[j] = Bs[k][tx*4+j];
#pragma unroll
      for (int i = 0; i < 4; ++i)
#pragma unroll
        for (int j = 0; j < 4; ++j) acc[i][j] = fmaf(av[i], bv[j], acc[i][j]);
    }
    __syncthreads();
  }
#pragma unroll
  for (int i = 0; i < 4; ++i) {
    int m = m0 + ty*4 + i;
#pragma unroll
    for (int j = 0; j < 4; ++j) {
      int n = n0 + tx*4 + j;
      float v = acc[i][j] + bias[n];
      if (RELU) v = fmaxf(v, 0.0f);
      C[(size_t)m * ldc + n] = v;
    }
  }
}

// ---------------- DAG scan kernel ----------------
// grid = 256 blocks: batch = blockIdx>>5, slice = blockIdx&31 (12 dims each)
struct ScanP {
  const float* Hl;      // q rows, stride CONC_
  float*       bufC;    // cached output rows, stride CONC_ (for later kernels)
  float*       hnX;     // [8,96,384] exchange (sentinel-filled, atomics)
  float*       MX;      // [8,96,384] exchange (sentinel-filled, atomics)
  const float* GIc;     // [768,1152] q@Wih_c^T + bih_c
  const float* GHp;     // [768,1152] q@Whh_p^T + bhh_p
  const float* Whhc;    // [1152,384]
  const float* Wihp;    // [1152,384]
  const float* bhhc;    // [1152]
  const float* bihp;    // [1152]
  const float* Wr0;     // [384,384]
  const float* Wr1;     // [384,384]
  const float* wk;      // [384] (enc only)
  const float* mask;    // enc: adj; dec: adjB (negated use)
  const float* smask;   // [8,96,96]
  float*       adjB;    // enc output (normal stores, read by later kernels)
};

template<int ENC>
__global__ __launch_bounds__(256)
void scan_kernel(ScanP p)
{
  const int tid  = threadIdx.x;
  const int b    = blockIdx.x >> 5;
  const int sl   = blockIdx.x & 31;
  const int j0   = sl * 12;
  const int team = tid >> 4, lane = tid & 15;

  __shared__ __align__(16) float stage[HID_];   // hn (P1) then M (P2)
  __shared__ float w_sm[N_];
  __shared__ float alpha[N_];                   // block-private alphak history
  __shared__ float dots[80];
  __shared__ float red4[4];
  __shared__ float sh_aknew;
  __shared__ float bufr0L[12][N_];
  __shared__ float bufr1L[12][N_];

  // ---- node 0 ----
  if (tid < 12) {
    int j = j0 + tid;
    const float* gi = p.GIc + (size_t)(b * N_) * GID_;
    const float* gh = p.GHp + (size_t)(b * N_) * GID_;
    float rc = sigf(gi[j] + p.bhhc[j]);
    float zc = sigf(gi[HID_ + j] + p.bhhc[HID_ + j]);
    float nc = tanhf(gi[2*HID_ + j] + rc * p.bhhc[2*HID_ + j]);
    float outc = (1.0f - zc) * nc;
    float rp = sigf(p.bihp[j] + gh[j]);
    float zp = sigf(p.bihp[HID_ + j] + gh[HID_ + j]);
    float np = tanhf(p.bihp[2*HID_ + j] + rp * gh[2*HID_ + j]);
    float x0 = p.Hl[(size_t)(b * N_) * CONC_ + j];
    float h0 = outc + (1.0f - zp) * np + zp * x0;
    p.bufC[(size_t)(b * N_) * CONC_ + j] = h0;
    atstf(&p.hnX[(size_t)(b * N_) * HID_ + j], h0);
  }

  for (int i = 1; i < N_; ++i) {
    // Prefetch the step-tail operands early (hide under the hn spin).
    float pf_gi0=0, pf_gi1=0, pf_gi2=0, pf_gh0=0, pf_gh1=0, pf_gh2=0, pf_q=0;
    if (tid < 12) {
      int j = j0 + tid;
      const float* gi = p.GIc + ((size_t)b * N_ + i) * GID_;
      const float* gh = p.GHp + ((size_t)b * N_ + i) * GID_;
      pf_gi0 = gi[j]; pf_gi1 = gi[HID_ + j]; pf_gi2 = gi[2*HID_ + j];
      pf_gh0 = gh[j]; pf_gh1 = gh[HID_ + j]; pf_gh2 = gh[2*HID_ + j];
      pf_q   = p.Hl[((size_t)b * N_ + i) * CONC_ + j];
    }

    // ---- P1a: spin-stage hn[i-1], compute bufr cols + aknew ----
    {
      const float* src = p.hnX + (size_t)(b * N_ + (i - 1)) * HID_;
      for (int k = tid; k < HID_; k += 256) stage[k] = spinld(&src[k]);
    }
    __syncthreads();
    const float4* st4 = (const float4*)stage;
    const int nd = ENC ? 25 : 24;
#pragma unroll
    for (int u = 0; u < 2; ++u) {
      int rr = team + u * 16;
      if (rr < nd) {
        const float* wrow;
        if (rr < 12)      wrow = p.Wr0 + (size_t)(j0 + rr) * HID_;
        else if (rr < 24) wrow = p.Wr1 + (size_t)(j0 + rr - 12) * HID_;
        else              wrow = p.wk;
        const float4* w4 = (const float4*)wrow;
        float acc = 0.f;
#pragma unroll
        for (int m = 0; m < 6; ++m) {
          float4 a = w4[lane + 16*m];
          float4 h = st4[lane + 16*m];
          acc = fmaf(a.x, h.x, acc); acc = fmaf(a.y, h.y, acc);
          acc = fmaf(a.z, h.z, acc); acc = fmaf(a.w, h.w, acc);
        }
#pragma unroll
        for (int mm = 8; mm; mm >>= 1) acc += __shfl_xor(acc, mm);
        if (lane == 0) {
          if (rr < 12)      bufr0L[rr][i - 1] = acc;
          else if (rr < 24) bufr1L[rr - 12][i - 1] = acc;
          else              sh_aknew = acc;
        }
      }
    }
    __syncthreads();

    // ---- P1b: attention weights w[0..i-1] ----
    if (ENC) {
      if (tid == 0) alpha[i - 1] = sh_aknew;
      float av = -3.0e38f;
      if (tid < i) {
        float ak = (tid == i - 1) ? sh_aknew : alpha[tid];
        float ad = p.mask[((size_t)b * N_ + i) * N_ + tid];
        av = ak - (1.0f - ad) * 1e30f;
      }
      float v = av;
#pragma unroll
      for (int m = 32; m; m >>= 1) v = fmaxf(v, __shfl_xor(v, m));
      if ((tid & 63) == 0) red4[tid >> 6] = v;
      __syncthreads();
      float mx = fmaxf(fmaxf(red4[0], red4[1]), fmaxf(red4[2], red4[3]));
      __syncthreads();
      float e = (tid < i) ? expf(av - mx) : 0.0f;
      v = e;
#pragma unroll
      for (int m = 32; m; m >>= 1) v += __shfl_xor(v, m);
      if ((tid & 63) == 0) red4[tid >> 6] = v;
      __syncthreads();
      float ssum = red4[0] + red4[1] + red4[2] + red4[3];
      if (tid < N_) w_sm[tid] = (tid < i) ? e / ssum : 0.0f;
      __syncthreads();
      if (sl == 0 && tid < N_)
        p.adjB[((size_t)b * N_ + i) * N_ + tid] = w_sm[tid];
    } else {
      if (tid < N_)
        w_sm[tid] = (tid < i) ? -p.mask[((size_t)b * N_ + i) * N_ + tid] : 0.0f;
      __syncthreads();
    }

    // ---- P1c: M[slice] = sum_n w[n]*(s*bufr0 + (1-s)*bufr1) -> publish ----
    const float* srow = p.smask + ((size_t)b * N_ + i) * N_;
    {
      int rr = team;                              // teams 0..11 active
      if (rr < 12) {
        float acc = 0.f;
        for (int n = lane; n < i; n += 16) {
          float sv = srow[n];
          acc = fmaf(w_sm[n], sv * bufr0L[rr][n] + (1.0f - sv) * bufr1L[rr][n], acc);
        }
#pragma unroll
        for (int mm = 8; mm; mm >>= 1) acc += __shfl_xor(acc, mm);
        if (lane == 0) atstf(&p.MX[((size_t)b * N_ + i) * HID_ + j0 + rr], acc);
      }
    }

    // ---- P2: spin-stage M[i], gate dots, combine, publish hn ----
    {
      const float* src = p.MX + (size_t)(b * N_ + i) * HID_;
      for (int k = tid; k < HID_; k += 256) stage[k] = spinld(&src[k]);
    }
    __syncthreads();
#pragma unroll
    for (int u = 0; u < 5; ++u) {
      int rr = team + u * 16;
      if (rr < 72) {
        int jl = rr % 12, g = rr / 12;           // 0..2 Whhc r/z/n, 3..5 Wihp r/z/n
        int row = j0 + jl + (g % 3) * HID_;
        const float4* w4 = (const float4*)((g < 3 ? p.Whhc : p.Wihp) + (size_t)row * HID_);
        float acc = 0.f;
#pragma unroll
        for (int m = 0; m < 6; ++m) {
          float4 a = w4[lane + 16*m];
          float4 h = st4[lane + 16*m];
          acc = fmaf(a.x, h.x, acc); acc = fmaf(a.y, h.y, acc);
          acc = fmaf(a.z, h.z, acc); acc = fmaf(a.w, h.w, acc);
        }
#pragma unroll
        for (int mm = 8; mm; mm >>= 1) acc += __shfl_xor(acc, mm);
        if (lane == 0) dots[rr] = acc;
      }
    }
    __syncthreads();
    if (tid < 12) {
      int j = j0 + tid;
      float Mj = stage[j];
      float rc = sigf(pf_gi0 + dots[tid] + p.bhhc[j]);
      float zc = sigf(pf_gi1 + dots[12 + tid] + p.bhhc[HID_ + j]);
      float nc = tanhf(pf_gi2 + rc * (dots[24 + tid] + p.bhhc[2*HID_ + j]));
      float outc = (1.0f - zc) * nc + zc * Mj;
      float rp = sigf(dots[36 + tid] + p.bihp[j] + pf_gh0);
      float zp = sigf(dots[48 + tid] + p.bihp[HID_ + j] + pf_gh1);
      float np = tanhf(dots[60 + tid] + p.bihp[2*HID_ + j] + rp * pf_gh2);
      float hv = outc + (1.0f - zp) * np + zp * pf_q;
      p.bufC[((size_t)b * N_ + i) * CONC_ + j] = hv;
      atstf(&p.hnX[((size_t)b * N_ + i) * HID_ + j], hv);
    }
    __syncthreads();   // protect stage[] before next iteration overwrites it
  }
}

// ---------------- feature_map = I - adjB2 (row 0 implicit 0) ----------------
__global__ __launch_bounds__(256)
void fmap_kernel(const float* __restrict__ adjB2, float* __restrict__ out)
{
  int idx = blockIdx.x * 256 + threadIdx.x;
  if (idx < B_ * N_ * N_) {
    int j = idx % N_;
    int i = (idx / N_) % N_;
    float a = (i == 0) ? 0.0f : adjB2[idx];
    out[idx] = ((i == j) ? 1.0f : 0.0f) - a;
  }
}

// ---------------- orchestration ----------------
extern "C" void kernel_launch(void* const* d_in, const int* in_sizes, int n_in,
                              void* d_out, int out_size, void* d_ws, size_t ws_size,
                              hipStream_t stream)
{
  (void)in_sizes; (void)n_in; (void)out_size; (void)ws_size;
  const float* features     = (const float*)d_in[0];
  const float* adj          = (const float*)d_in[1];
  const float* s_mask       = (const float*)d_in[2];
  const float* enc_fc1_W    = (const float*)d_in[5];
  const float* enc_fc1_b    = (const float*)d_in[6];
  const float* enc_gat_w    = (const float*)d_in[7];
  const float* enc_Wr0      = (const float*)d_in[9];
  const float* enc_Wr1      = (const float*)d_in[10];
  const float* enc_gruc_Wih = (const float*)d_in[11];
  const float* enc_gruc_Whh = (const float*)d_in[12];
  const float* enc_gruc_bih = (const float*)d_in[13];
  const float* enc_gruc_bhh = (const float*)d_in[14];
  const float* enc_grup_Wih = (const float*)d_in[15];
  const float* enc_grup_Whh = (const float*)d_in[16];
  const float* enc_grup_bih = (const float*)d_in[17];
  const float* enc_grup_bhh = (const float*)d_in[18];
  const float* enc_mlp_W0   = (const float*)d_in[19];
  const float* enc_mlp_b0   = (const float*)d_in[20];
  const float* enc_mlp_W1   = (const float*)d_in[21];
  const float* enc_mlp_b1   = (const float*)d_in[22];
  const float* dec_fc1_W    = (const float*)d_in[23];
  const float* dec_fc1_b    = (const float*)d_in[24];
  const float* dec_Wr0      = (const float*)d_in[25];
  const float* dec_Wr1      = (const float*)d_in[26];
  const float* dec_gruc_Wih = (const float*)d_in[27];
  const float* dec_gruc_Whh = (const float*)d_in[28];
  const float* dec_gruc_bih = (const float*)d_in[29];
  const float* dec_gruc_bhh = (const float*)d_in[30];
  const float* dec_grup_Wih = (const float*)d_in[31];
  const float* dec_grup_Whh = (const float*)d_in[32];
  const float* dec_grup_bih = (const float*)d_in[33];
  const float* dec_grup_bhh = (const float*)d_in[34];
  const float* dec_mlp_W0   = (const float*)d_in[35];
  const float* dec_mlp_b0   = (const float*)d_in[36];
  const float* dec_mlp_W1   = (const float*)d_in[37];
  const float* dec_mlp_b1   = (const float*)d_in[38];

  float* ws = (float*)d_ws;
  size_t o = 0;
  float* Hse   = ws + o; o += (size_t)B_ * N_ * CONC_;
  float* Hsd   = ws + o; o += (size_t)B_ * N_ * CONC_;
  float* GIc   = ws + o; o += (size_t)B_ * N_ * GID_;
  float* GHp   = ws + o; o += (size_t)B_ * N_ * GID_;
  float* adjB1 = ws + o; o += (size_t)B_ * N_ * N_;
  float* adjB2 = ws + o; o += (size_t)B_ * N_ * N_;
  float* fU    = ws + o; o += (size_t)B_ * N_ * CODE_;
  float* Tmp   = ws + o; o += (size_t)B_ * N_ * HID_;
  float* hnX   = ws + o; o += (size_t)B_ * N_ * HID_;
  float* MX    = ws + o; o += (size_t)B_ * N_ * HID_;
  const size_t xch_bytes = (size_t)2 * B_ * N_ * HID_ * sizeof(float);

  const dim3 blk(256);
  float* logits = (float*)d_out;
  float* fmap   = (float*)d_out + (size_t)B_ * N_ * FEAT_;

  // encoder fc1
  gemm_bias<1><<<dim3(6, 12), blk, 0, stream>>>(features, EMB_, enc_fc1_W, enc_fc1_b,
                                                Hse, CONC_, EMB_);
  // encoder scans
  for (int l = 0; l < 2; ++l) {
    const float* Hl = Hse + l * HID_;
    gemm_bias<0><<<dim3(18, 12), blk, 0, stream>>>(Hl, CONC_,
        enc_gruc_Wih + (size_t)l * GID_ * HID_, enc_gruc_bih + l * GID_, GIc, GID_, HID_);
    gemm_bias<0><<<dim3(18, 12), blk, 0, stream>>>(Hl, CONC_,
        enc_grup_Whh + (size_t)l * GID_ * HID_, enc_grup_bhh + l * GID_, GHp, GID_, HID_);
    hipMemsetAsync(hnX, 0xFF, xch_bytes, stream);   // sentinel-fill hnX+MX
    ScanP p;
    p.Hl = Hl; p.bufC = Hse + (l + 1) * HID_;
    p.hnX = hnX; p.MX = MX;
    p.GIc = GIc; p.GHp = GHp;
    p.Whhc = enc_gruc_Whh + (size_t)l * GID_ * HID_;
    p.Wihp = enc_grup_Wih + (size_t)l * GID_ * HID_;
    p.bhhc = enc_gruc_bhh + l * GID_;
    p.bihp = enc_grup_bih + l * GID_;
    p.Wr0 = enc_Wr0 + (size_t)l * HID_ * HID_;
    p.Wr1 = enc_Wr1 + (size_t)l * HID_ * HID_;
    p.wk = enc_gat_w + l * 2 * HID_ + HID_;
    p.mask = adj; p.smask = s_mask;
    p.adjB = (l == 0) ? adjB1 : adjB2;
    scan_kernel<1><<<dim3(256), blk, 0, stream>>>(p);
  }
  // encoder MLP -> fU
  gemm_bias<1><<<dim3(6, 12), blk, 0, stream>>>(Hse, CONC_, enc_mlp_W0, enc_mlp_b0,
                                                Tmp, HID_, CONC_);
  gemm_bias<0><<<dim3(3, 12), blk, 0, stream>>>(Tmp, HID_, enc_mlp_W1, enc_mlp_b1,
                                                fU, CODE_, HID_);
  // decoder fc1
  gemm_bias<1><<<dim3(6, 12), blk, 0, stream>>>(fU, CODE_, dec_fc1_W, dec_fc1_b,
                                                Hsd, CONC_, CODE_);
  // decoder scans
  for (int l = 0; l < 2; ++l) {
    const float* Hl = Hsd + l * HID_;
    gemm_bias<0><<<dim3(18, 12), blk, 0, stream>>>(Hl, CONC_,
        dec_gruc_Wih + (size_t)l * GID_ * HID_, dec_gruc_bih + l * GID_, GIc, GID_, HID_);
    gemm_bias<0><<<dim3(18, 12), blk, 0, stream>>>(Hl, CONC_,
        dec_grup_Whh + (size_t)l * GID_ * HID_, dec_grup_bhh + l * GID_, GHp, GID_, HID_);
    hipMemsetAsync(hnX, 0xFF, xch_bytes, stream);
    ScanP p;
    p.Hl = Hl; p.bufC = Hsd + (l + 1) * HID_;
    p.hnX = hnX; p.MX = MX;
    p.GIc = GIc; p.GHp = GHp;
    p.Whhc = dec_gruc_Whh + (size_t)l * GID_ * HID_;
    p.Wihp = dec_grup_Wih + (size_t)l * GID_ * HID_;
    p.bhhc = dec_gruc_bhh + l * GID_;
    p.bihp = dec_grup_bih + l * GID_;
    p.Wr0 = dec_Wr0 + (size_t)l * HID_ * HID_;
    p.Wr1 = dec_Wr1 + (size_t)l * HID_ * HID_;
    p.wk = nullptr;
    p.mask = (l == 0) ? adjB1 : adjB2;   // w[n] = -adjB[b,i,n] for n<i
    p.smask = s_mask;
    p.adjB = nullptr;
    scan_kernel<0><<<dim3(256), blk, 0, stream>>>(p);
  }
  // decoder MLP -> logits
  gemm_bias<1><<<dim3(6, 12), blk, 0, stream>>>(Hsd, CONC_, dec_mlp_W0, dec_mlp_b0,
                                                Tmp, HID_, CONC_);
  gemm_bias<0><<<dim3(12, 12), blk, 0, stream>>>(Tmp, HID_, dec_mlp_W1, dec_mlp_b1,
                                                 logits, FEAT_, HID_);
  // feature_map
  fmap_kernel<<<dim3((B_ * N_ * N_ + 255) / 256), blk, 0, stream>>>(adjB2, fmap);
}

// Round 4
// 3384.625 us; speedup vs baseline: 1.3345x; 1.3345x over previous
//
#include <hip/hip_runtime.h>
#include <math.h>

#define B_    8
#define N_    96
#define EMB_  768
#define HID_  384
#define GID_  1152   // 3*HID
#define CONC_ 1152   // (L+1)*HID
#define CODE_ 192
#define FEAT_ 768

__device__ __forceinline__ float sigf(float x) { return 1.0f / (1.0f + expf(-x)); }

// LLC-coherent (agent-scope) relaxed atomic accessors (proven visibility path).
__device__ __forceinline__ void atstf(float* p, float v) {
  __hip_atomic_store(p, v, __ATOMIC_RELAXED, __HIP_MEMORY_SCOPE_AGENT);
}
__device__ __forceinline__ float atldf(const float* p) {
  return __hip_atomic_load((float*)p, __ATOMIC_RELAXED, __HIP_MEMORY_SCOPE_AGENT);
}
__device__ __forceinline__ unsigned atldu(const unsigned* p) {
  return __hip_atomic_load((unsigned*)p, __ATOMIC_RELAXED, __HIP_MEMORY_SCOPE_AGENT);
}
__device__ __forceinline__ void atstu(unsigned* p, unsigned v) {
  __hip_atomic_store(p, v, __ATOMIC_RELAXED, __HIP_MEMORY_SCOPE_AGENT);
}
__device__ __forceinline__ float dot4(float4 a, float4 b) {
  return fmaf(a.x, b.x, fmaf(a.y, b.y, fmaf(a.z, b.z, a.w * b.w)));
}

// ---------------- generic GEMM: C[M,N] = act(A @ W^T + bias) ----------------
template<int RELU>
__global__ __launch_bounds__(256)
void gemm_bias(const float* __restrict__ A, int lda,
               const float* __restrict__ W,
               const float* __restrict__ bias,
               float* __restrict__ C, int ldc, int K)
{
  __shared__ float As[16][68];
  __shared__ float Bs[16][68];
  const int tid = threadIdx.x;
  const int m0 = blockIdx.y * 64;
  const int n0 = blockIdx.x * 64;
  const int lr = tid >> 2;
  const int lc = (tid & 3) * 4;
  const int ty = tid >> 4, tx = tid & 15;
  float acc[4][4] = {};
  for (int k0 = 0; k0 < K; k0 += 16) {
    float4 a4 = *(const float4*)(A + (size_t)(m0 + lr) * lda + k0 + lc);
    float4 b4 = *(const float4*)(W + (size_t)(n0 + lr) * K + k0 + lc);
    As[lc+0][lr] = a4.x; As[lc+1][lr] = a4.y; As[lc+2][lr] = a4.z; As[lc+3][lr] = a4.w;
    Bs[lc+0][lr] = b4.x; Bs[lc+1][lr] = b4.y; Bs[lc+2][lr] = b4.z; Bs[lc+3][lr] = b4.w;
    __syncthreads();
#pragma unroll
    for (int k = 0; k < 16; ++k) {
      float av[4], bv[4];
#pragma unroll
      for (int i = 0; i < 4; ++i) av[i] = As[k][ty*4+i];
#pragma unroll
      for (int j = 0; j < 4; ++j) bv[j] = Bs[k][tx*4+j];
#pragma unroll
      for (int i = 0; i < 4; ++i)
#pragma unroll
        for (int j = 0; j < 4; ++j) acc[i][j] = fmaf(av[i], bv[j], acc[i][j]);
    }
    __syncthreads();
  }
#pragma unroll
  for (int i = 0; i < 4; ++i) {
    int m = m0 + ty*4 + i;
#pragma unroll
    for (int j = 0; j < 4; ++j) {
      int n = n0 + tx*4 + j;
      float v = acc[i][j] + bias[n];
      if (RELU) v = fmaxf(v, 0.0f);
      C[(size_t)m * ldc + n] = v;
    }
  }
}

// ---------------- DAG scan kernel ----------------
// grid = 256 blocks: batch = blockIdx>>5, slice = blockIdx&31 (12 dims each)
struct ScanP {
  const float* Hl;      // q rows, stride CONC_
  float*       bufC;    // cached output rows, stride CONC_ (for later kernels)
  float*       hnX;     // [8,96,384] exchange (atomics, flag-gated)
  float*       MX;      // [8,96,384] exchange (atomics, flag-gated)
  unsigned*    flags;   // [4][2][8][96][32] zeroed once per launch
  const float* GIc;     // [768,1152] q@Wih_c^T + bih_c
  const float* GHp;     // [768,1152] q@Whh_p^T + bhh_p
  const float* Whhc;    // [1152,384]
  const float* Wihp;    // [1152,384]
  const float* bhhc;    // [1152]
  const float* bihp;    // [1152]
  const float* Wr0;     // [384,384]
  const float* Wr1;     // [384,384]
  const float* wk;      // [384] (enc only)
  const float* mask;    // enc: adj; dec: adjB (negated use)
  const float* smask;   // [8,96,96]
  float*       adjB;    // enc output
  int          scan;    // 0..3
};

template<int ENC>
__global__ __launch_bounds__(256, 1)
void scan_kernel(ScanP p)
{
  const int tid  = threadIdx.x;
  const int b    = blockIdx.x >> 5;
  const int sl   = blockIdx.x & 31;
  const int j0   = sl * 12;
  const int team = tid >> 4, lane = tid & 15;

  __shared__ __align__(16) float stage[HID_];   // hn (P1) then M (P2)
  __shared__ float w_sm[N_];
  __shared__ float alpha[N_];
  __shared__ float dots[80];
  __shared__ float red4[4];
  __shared__ float sh_aknew;
  __shared__ float bufr0L[12][N_];
  __shared__ float bufr1L[12][N_];

  // flag region bases: [scan][ph][b][i][32]
  unsigned* flagHN = p.flags + ((((size_t)p.scan * 2 + 0) * 8 + b) * 96) * 32;
  unsigned* flagM  = p.flags + ((((size_t)p.scan * 2 + 1) * 8 + b) * 96) * 32;

  // producer epilogue: drain this block's atomic stores, then set own flag
#define PUBLISH_FLAG(arr, i_)                                                \
  do {                                                                       \
    asm volatile("s_waitcnt vmcnt(0)" ::: "memory");                         \
    __syncthreads();                                                         \
    if (tid == 0) atstu(&(arr)[(size_t)(i_) * 32 + sl], 1u);                 \
  } while (0)

  // consumer: lanes 0..31 spin each on one slice flag, then barrier
#define WAIT_FLAG(arr, i_)                                                   \
  do {                                                                       \
    if (tid < 32) {                                                          \
      const unsigned* f_ = &(arr)[(size_t)(i_) * 32 + tid];                  \
      while (atldu(f_) == 0u) {}                                             \
    }                                                                        \
    __syncthreads();                                                         \
  } while (0)

  // ---- node 0 ----
  if (tid < 12) {
    int j = j0 + tid;
    const float* gi = p.GIc + (size_t)(b * N_) * GID_;
    const float* gh = p.GHp + (size_t)(b * N_) * GID_;
    float rc = sigf(gi[j] + p.bhhc[j]);
    float zc = sigf(gi[HID_ + j] + p.bhhc[HID_ + j]);
    float nc = tanhf(gi[2*HID_ + j] + rc * p.bhhc[2*HID_ + j]);
    float outc = (1.0f - zc) * nc;
    float rp = sigf(p.bihp[j] + gh[j]);
    float zp = sigf(p.bihp[HID_ + j] + gh[HID_ + j]);
    float np = tanhf(p.bihp[2*HID_ + j] + rp * gh[2*HID_ + j]);
    float x0 = p.Hl[(size_t)(b * N_) * CONC_ + j];
    float h0 = outc + (1.0f - zp) * np + zp * x0;
    p.bufC[(size_t)(b * N_) * CONC_ + j] = h0;
    atstf(&p.hnX[(size_t)(b * N_) * HID_ + j], h0);
  }
  PUBLISH_FLAG(flagHN, 0);

  const int nd = ENC ? 25 : 24;

  for (int i = 1; i < N_; ++i) {
    // ---- preload P1a weight rows into registers (rows team, team+16) ----
    const int rA0 = team, rA1 = team + 16;
    const float* wr0p = (rA0 < 12) ? p.Wr0 + (size_t)(j0 + rA0) * HID_
                                   : p.Wr1 + (size_t)(j0 + rA0 - 12) * HID_;
    const float* wr1p;
    if (rA1 < 24)       wr1p = p.Wr1 + (size_t)(j0 + rA1 - 12) * HID_;
    else if (rA1 < nd)  wr1p = p.wk;
    else                wr1p = wr0p;          // dummy, result unused
    float4 wA0[6], wA1[6];
#pragma unroll
    for (int m = 0; m < 6; ++m) {
      wA0[m] = ((const float4*)wr0p)[lane + 16*m];
      wA1[m] = ((const float4*)wr1p)[lane + 16*m];
    }
    // prefetch step-tail operands
    float pf_gi0=0, pf_gi1=0, pf_gi2=0, pf_gh0=0, pf_gh1=0, pf_gh2=0, pf_q=0;
    if (tid < 12) {
      int j = j0 + tid;
      const float* gi = p.GIc + ((size_t)b * N_ + i) * GID_;
      const float* gh = p.GHp + ((size_t)b * N_ + i) * GID_;
      pf_gi0 = gi[j]; pf_gi1 = gi[HID_ + j]; pf_gi2 = gi[2*HID_ + j];
      pf_gh0 = gh[j]; pf_gh1 = gh[HID_ + j]; pf_gh2 = gh[2*HID_ + j];
      pf_q   = p.Hl[((size_t)b * N_ + i) * CONC_ + j];
    }

    // ---- wait for hn[i-1], bulk-stage it ----
    WAIT_FLAG(flagHN, i - 1);
    {
      const float* src = p.hnX + (size_t)(b * N_ + (i - 1)) * HID_;
      for (int k = tid; k < HID_; k += 256) stage[k] = atldf(&src[k]);
    }
    __syncthreads();
    const float4* st4 = (const float4*)stage;
    float4 hreg[6];
#pragma unroll
    for (int m = 0; m < 6; ++m) hreg[m] = st4[lane + 16*m];

    // ---- P1a: bufr columns + aknew ----
    {
      float a0 = 0.f, a1 = 0.f;
#pragma unroll
      for (int m = 0; m < 6; ++m) {
        a0 += dot4(wA0[m], hreg[m]);
        a1 += dot4(wA1[m], hreg[m]);
      }
#pragma unroll
      for (int mm = 8; mm; mm >>= 1) {
        a0 += __shfl_xor(a0, mm);
        a1 += __shfl_xor(a1, mm);
      }
      if (lane == 0) {
        if (rA0 < 12) bufr0L[rA0][i - 1] = a0;
        else          bufr1L[rA0 - 12][i - 1] = a0;
        if (rA1 < 24)      bufr1L[rA1 - 12][i - 1] = a1;
        else if (rA1 < nd) sh_aknew = a1;
      }
    }
    __syncthreads();

    // ---- P1b: attention weights w[0..i-1] ----
    if (ENC) {
      if (tid == 0) alpha[i - 1] = sh_aknew;
      float av = -3.0e38f;
      if (tid < i) {
        float ak = (tid == i - 1) ? sh_aknew : alpha[tid];
        float ad = p.mask[((size_t)b * N_ + i) * N_ + tid];
        av = ak - (1.0f - ad) * 1e30f;
      }
      float v = av;
#pragma unroll
      for (int m = 32; m; m >>= 1) v = fmaxf(v, __shfl_xor(v, m));
      if ((tid & 63) == 0) red4[tid >> 6] = v;
      __syncthreads();
      float mx = fmaxf(fmaxf(red4[0], red4[1]), fmaxf(red4[2], red4[3]));
      __syncthreads();
      float e = (tid < i) ? expf(av - mx) : 0.0f;
      v = e;
#pragma unroll
      for (int m = 32; m; m >>= 1) v += __shfl_xor(v, m);
      if ((tid & 63) == 0) red4[tid >> 6] = v;
      __syncthreads();
      float ssum = red4[0] + red4[1] + red4[2] + red4[3];
      if (tid < N_) w_sm[tid] = (tid < i) ? e / ssum : 0.0f;
      __syncthreads();
      if (sl == 0 && tid < N_)
        p.adjB[((size_t)b * N_ + i) * N_ + tid] = w_sm[tid];
    } else {
      if (tid < N_)
        w_sm[tid] = (tid < i) ? -p.mask[((size_t)b * N_ + i) * N_ + tid] : 0.0f;
      __syncthreads();
    }

    // ---- preload P2 gate-weight rows (5 per team) ----
    float4 wB[5][6];
#pragma unroll
    for (int u = 0; u < 5; ++u) {
      int rr = team + u * 16;
      if (rr < 72) {
        int jl = rr % 12, g = rr / 12;
        const float4* w4 = (const float4*)((g < 3 ? p.Whhc : p.Wihp)
                             + (size_t)(j0 + jl + (g % 3) * HID_) * HID_);
#pragma unroll
        for (int m = 0; m < 6; ++m) wB[u][m] = w4[lane + 16*m];
      }
    }

    // ---- P1c: M[slice] -> publish ----
    const float* srow = p.smask + ((size_t)b * N_ + i) * N_;
    if (team < 12) {
      float acc = 0.f;
      for (int n = lane; n < i; n += 16) {
        float sv = srow[n];
        acc = fmaf(w_sm[n], sv * bufr0L[team][n] + (1.0f - sv) * bufr1L[team][n], acc);
      }
#pragma unroll
      for (int mm = 8; mm; mm >>= 1) acc += __shfl_xor(acc, mm);
      if (lane == 0) atstf(&p.MX[((size_t)b * N_ + i) * HID_ + j0 + team], acc);
    }
    PUBLISH_FLAG(flagM, i);

    // ---- wait for full M, bulk-stage it ----
    WAIT_FLAG(flagM, i);
    {
      const float* src = p.MX + (size_t)(b * N_ + i) * HID_;
      for (int k = tid; k < HID_; k += 256) stage[k] = atldf(&src[k]);
    }
    __syncthreads();
    float4 mreg[6];
#pragma unroll
    for (int m = 0; m < 6; ++m) mreg[m] = st4[lane + 16*m];

    // ---- P2: gate dots from registers ----
#pragma unroll
    for (int u = 0; u < 5; ++u) {
      int rr = team + u * 16;
      if (rr < 72) {
        float acc = 0.f;
#pragma unroll
        for (int m = 0; m < 6; ++m) acc += dot4(wB[u][m], mreg[m]);
#pragma unroll
        for (int mm = 8; mm; mm >>= 1) acc += __shfl_xor(acc, mm);
        if (lane == 0) dots[rr] = acc;
      }
    }
    __syncthreads();
    if (tid < 12) {
      int j = j0 + tid;
      float Mj = stage[j];
      float rc = sigf(pf_gi0 + dots[tid] + p.bhhc[j]);
      float zc = sigf(pf_gi1 + dots[12 + tid] + p.bhhc[HID_ + j]);
      float nc = tanhf(pf_gi2 + rc * (dots[24 + tid] + p.bhhc[2*HID_ + j]));
      float outc = (1.0f - zc) * nc + zc * Mj;
      float rp = sigf(dots[36 + tid] + p.bihp[j] + pf_gh0);
      float zp = sigf(dots[48 + tid] + p.bihp[HID_ + j] + pf_gh1);
      float np = tanhf(dots[60 + tid] + p.bihp[2*HID_ + j] + rp * pf_gh2);
      float hv = outc + (1.0f - zp) * np + zp * pf_q;
      p.bufC[((size_t)b * N_ + i) * CONC_ + j] = hv;
      atstf(&p.hnX[((size_t)b * N_ + i) * HID_ + j], hv);
    }
    PUBLISH_FLAG(flagHN, i);
  }
#undef PUBLISH_FLAG
#undef WAIT_FLAG
}

// ---------------- feature_map = I - adjB2 (row 0 implicit 0) ----------------
__global__ __launch_bounds__(256)
void fmap_kernel(const float* __restrict__ adjB2, float* __restrict__ out)
{
  int idx = blockIdx.x * 256 + threadIdx.x;
  if (idx < B_ * N_ * N_) {
    int j = idx % N_;
    int i = (idx / N_) % N_;
    float a = (i == 0) ? 0.0f : adjB2[idx];
    out[idx] = ((i == j) ? 1.0f : 0.0f) - a;
  }
}

// ---------------- orchestration ----------------
extern "C" void kernel_launch(void* const* d_in, const int* in_sizes, int n_in,
                              void* d_out, int out_size, void* d_ws, size_t ws_size,
                              hipStream_t stream)
{
  (void)in_sizes; (void)n_in; (void)out_size; (void)ws_size;
  const float* features     = (const float*)d_in[0];
  const float* adj          = (const float*)d_in[1];
  const float* s_mask       = (const float*)d_in[2];
  const float* enc_fc1_W    = (const float*)d_in[5];
  const float* enc_fc1_b    = (const float*)d_in[6];
  const float* enc_gat_w    = (const float*)d_in[7];
  const float* enc_Wr0      = (const float*)d_in[9];
  const float* enc_Wr1      = (const float*)d_in[10];
  const float* enc_gruc_Wih = (const float*)d_in[11];
  const float* enc_gruc_Whh = (const float*)d_in[12];
  const float* enc_gruc_bih = (const float*)d_in[13];
  const float* enc_gruc_bhh = (const float*)d_in[14];
  const float* enc_grup_Wih = (const float*)d_in[15];
  const float* enc_grup_Whh = (const float*)d_in[16];
  const float* enc_grup_bih = (const float*)d_in[17];
  const float* enc_grup_bhh = (const float*)d_in[18];
  const float* enc_mlp_W0   = (const float*)d_in[19];
  const float* enc_mlp_b0   = (const float*)d_in[20];
  const float* enc_mlp_W1   = (const float*)d_in[21];
  const float* enc_mlp_b1   = (const float*)d_in[22];
  const float* dec_fc1_W    = (const float*)d_in[23];
  const float* dec_fc1_b    = (const float*)d_in[24];
  const float* dec_Wr0      = (const float*)d_in[25];
  const float* dec_Wr1      = (const float*)d_in[26];
  const float* dec_gruc_Wih = (const float*)d_in[27];
  const float* dec_gruc_Whh = (const float*)d_in[28];
  const float* dec_gruc_bih = (const float*)d_in[29];
  const float* dec_gruc_bhh = (const float*)d_in[30];
  const float* dec_grup_Wih = (const float*)d_in[31];
  const float* dec_grup_Whh = (const float*)d_in[32];
  const float* dec_grup_bih = (const float*)d_in[33];
  const float* dec_grup_bhh = (const float*)d_in[34];
  const float* dec_mlp_W0   = (const float*)d_in[35];
  const float* dec_mlp_b0   = (const float*)d_in[36];
  const float* dec_mlp_W1   = (const float*)d_in[37];
  const float* dec_mlp_b1   = (const float*)d_in[38];

  float* ws = (float*)d_ws;
  size_t o = 0;
  float* Hse   = ws + o; o += (size_t)B_ * N_ * CONC_;
  float* Hsd   = ws + o; o += (size_t)B_ * N_ * CONC_;
  float* GIc   = ws + o; o += (size_t)B_ * N_ * GID_;
  float* GHp   = ws + o; o += (size_t)B_ * N_ * GID_;
  float* adjB1 = ws + o; o += (size_t)B_ * N_ * N_;
  float* adjB2 = ws + o; o += (size_t)B_ * N_ * N_;
  float* fU    = ws + o; o += (size_t)B_ * N_ * CODE_;
  float* Tmp   = ws + o; o += (size_t)B_ * N_ * HID_;
  float* hnX   = ws + o; o += (size_t)B_ * N_ * HID_;
  float* MX    = ws + o; o += (size_t)B_ * N_ * HID_;
  unsigned* flags = (unsigned*)(ws + o);
  const size_t flag_bytes = (size_t)4 * 2 * B_ * N_ * 32 * sizeof(unsigned);

  const dim3 blk(256);
  float* logits = (float*)d_out;
  float* fmap   = (float*)d_out + (size_t)B_ * N_ * FEAT_;

  // zero ALL flags once for the whole launch (written once each per launch)
  hipMemsetAsync(flags, 0, flag_bytes, stream);

  // encoder fc1
  gemm_bias<1><<<dim3(6, 12), blk, 0, stream>>>(features, EMB_, enc_fc1_W, enc_fc1_b,
                                                Hse, CONC_, EMB_);
  // encoder scans
  for (int l = 0; l < 2; ++l) {
    const float* Hl = Hse + l * HID_;
    gemm_bias<0><<<dim3(18, 12), blk, 0, stream>>>(Hl, CONC_,
        enc_gruc_Wih + (size_t)l * GID_ * HID_, enc_gruc_bih + l * GID_, GIc, GID_, HID_);
    gemm_bias<0><<<dim3(18, 12), blk, 0, stream>>>(Hl, CONC_,
        enc_grup_Whh + (size_t)l * GID_ * HID_, enc_grup_bhh + l * GID_, GHp, GID_, HID_);
    ScanP p;
    p.Hl = Hl; p.bufC = Hse + (l + 1) * HID_;
    p.hnX = hnX; p.MX = MX; p.flags = flags;
    p.GIc = GIc; p.GHp = GHp;
    p.Whhc = enc_gruc_Whh + (size_t)l * GID_ * HID_;
    p.Wihp = enc_grup_Wih + (size_t)l * GID_ * HID_;
    p.bhhc = enc_gruc_bhh + l * GID_;
    p.bihp = enc_grup_bih + l * GID_;
    p.Wr0 = enc_Wr0 + (size_t)l * HID_ * HID_;
    p.Wr1 = enc_Wr1 + (size_t)l * HID_ * HID_;
    p.wk = enc_gat_w + l * 2 * HID_ + HID_;
    p.mask = adj; p.smask = s_mask;
    p.adjB = (l == 0) ? adjB1 : adjB2;
    p.scan = l;
    scan_kernel<1><<<dim3(256), blk, 0, stream>>>(p);
  }
  // encoder MLP -> fU
  gemm_bias<1><<<dim3(6, 12), blk, 0, stream>>>(Hse, CONC_, enc_mlp_W0, enc_mlp_b0,
                                                Tmp, HID_, CONC_);
  gemm_bias<0><<<dim3(3, 12), blk, 0, stream>>>(Tmp, HID_, enc_mlp_W1, enc_mlp_b1,
                                                fU, CODE_, HID_);
  // decoder fc1
  gemm_bias<1><<<dim3(6, 12), blk, 0, stream>>>(fU, CODE_, dec_fc1_W, dec_fc1_b,
                                                Hsd, CONC_, CODE_);
  // decoder scans
  for (int l = 0; l < 2; ++l) {
    const float* Hl = Hsd + l * HID_;
    gemm_bias<0><<<dim3(18, 12), blk, 0, stream>>>(Hl, CONC_,
        dec_gruc_Wih + (size_t)l * GID_ * HID_, dec_gruc_bih + l * GID_, GIc, GID_, HID_);
    gemm_bias<0><<<dim3(18, 12), blk, 0, stream>>>(Hl, CONC_,
        dec_grup_Whh + (size_t)l * GID_ * HID_, dec_grup_bhh + l * GID_, GHp, GID_, HID_);
    ScanP p;
    p.Hl = Hl; p.bufC = Hsd + (l + 1) * HID_;
    p.hnX = hnX; p.MX = MX; p.flags = flags;
    p.GIc = GIc; p.GHp = GHp;
    p.Whhc = dec_gruc_Whh + (size_t)l * GID_ * HID_;
    p.Wihp = dec_grup_Wih + (size_t)l * GID_ * HID_;
    p.bhhc = dec_gruc_bhh + l * GID_;
    p.bihp = dec_grup_bih + l * GID_;
    p.Wr0 = dec_Wr0 + (size_t)l * HID_ * HID_;
    p.Wr1 = dec_Wr1 + (size_t)l * HID_ * HID_;
    p.wk = nullptr;
    p.mask = (l == 0) ? adjB1 : adjB2;   // w[n] = -adjB[b,i,n] for n<i
    p.smask = s_mask;
    p.adjB = nullptr;
    p.scan = 2 + l;
    scan_kernel<0><<<dim3(256), blk, 0, stream>>>(p);
  }
  // decoder MLP -> logits
  gemm_bias<1><<<dim3(6, 12), blk, 0, stream>>>(Hsd, CONC_, dec_mlp_W0, dec_mlp_b0,
                                                Tmp, HID_, CONC_);
  gemm_bias<0><<<dim3(12, 12), blk, 0, stream>>>(Tmp, HID_, dec_mlp_W1, dec_mlp_b1,
                                                 logits, FEAT_, HID_);
  // feature_map
  fmap_kernel<<<dim3((B_ * N_ * N_ + 255) / 256), blk, 0, stream>>>(adjB2, fmap);
}

// Round 5
// 2474.257 us; speedup vs baseline: 1.8254x; 1.3679x over previous
//
#include <hip/hip_runtime.h>
#include <math.h>

#define B_    8
#define N_    96
#define EMB_  768
#define HID_  384
#define GID_  1152   // 3*HID
#define CONC_ 1152   // (L+1)*HID
#define CODE_ 192
#define FEAT_ 768

__device__ __forceinline__ float sigf(float x) { return 1.0f / (1.0f + expf(-x)); }

// LLC-coherent (agent-scope) relaxed atomic accessors (proven visibility path).
__device__ __forceinline__ void atstf(float* p, float v) {
  __hip_atomic_store(p, v, __ATOMIC_RELAXED, __HIP_MEMORY_SCOPE_AGENT);
}
__device__ __forceinline__ float atldf(const float* p) {
  return __hip_atomic_load((float*)p, __ATOMIC_RELAXED, __HIP_MEMORY_SCOPE_AGENT);
}
__device__ __forceinline__ float dot4(float4 a, float4 b) {
  return fmaf(a.x, b.x, fmaf(a.y, b.y, fmaf(a.z, b.z, a.w * b.w)));
}

// ---------------- generic GEMM: C[M,N] = act(A @ W^T + bias) ----------------
template<int RELU>
__global__ __launch_bounds__(256)
void gemm_bias(const float* __restrict__ A, int lda,
               const float* __restrict__ W,
               const float* __restrict__ bias,
               float* __restrict__ C, int ldc, int K)
{
  __shared__ float As[16][68];
  __shared__ float Bs[16][68];
  const int tid = threadIdx.x;
  const int m0 = blockIdx.y * 64;
  const int n0 = blockIdx.x * 64;
  const int lr = tid >> 2;
  const int lc = (tid & 3) * 4;
  const int ty = tid >> 4, tx = tid & 15;
  float acc[4][4] = {};
  for (int k0 = 0; k0 < K; k0 += 16) {
    float4 a4 = *(const float4*)(A + (size_t)(m0 + lr) * lda + k0 + lc);
    float4 b4 = *(const float4*)(W + (size_t)(n0 + lr) * K + k0 + lc);
    As[lc+0][lr] = a4.x; As[lc+1][lr] = a4.y; As[lc+2][lr] = a4.z; As[lc+3][lr] = a4.w;
    Bs[lc+0][lr] = b4.x; Bs[lc+1][lr] = b4.y; Bs[lc+2][lr] = b4.z; Bs[lc+3][lr] = b4.w;
    __syncthreads();
#pragma unroll
    for (int k = 0; k < 16; ++k) {
      float av[4], bv[4];
#pragma unroll
      for (int i = 0; i < 4; ++i) av[i] = As[k][ty*4+i];
#pragma unroll
      for (int j = 0; j < 4; ++j) bv[j] = Bs[k][tx*4+j];
#pragma unroll
      for (int i = 0; i < 4; ++i)
#pragma unroll
        for (int j = 0; j < 4; ++j) acc[i][j] = fmaf(av[i], bv[j], acc[i][j]);
    }
    __syncthreads();
  }
#pragma unroll
  for (int i = 0; i < 4; ++i) {
    int m = m0 + ty*4 + i;
#pragma unroll
    for (int j = 0; j < 4; ++j) {
      int n = n0 + tx*4 + j;
      float v = acc[i][j] + bias[n];
      if (RELU) v = fmaxf(v, 0.0f);
      C[(size_t)m * ldc + n] = v;
    }
  }
}

// ---------------- DAG scan kernel ----------------
// grid = 256 blocks: batch = blockIdx>>5, slice = blockIdx&31 (12 dims each)
struct ScanP {
  const float* Hl;      // q rows, stride CONC_
  float*       bufC;    // cached output rows, stride CONC_ (for later kernels)
  float*       hnX;     // [8,96,384] exchange (sentinel-filled, atomics)
  float*       MX;      // [8,96,384] exchange (sentinel-filled, atomics)
  const float* GIc;     // [768,1152] q@Wih_c^T + bih_c
  const float* GHp;     // [768,1152] q@Whh_p^T + bhh_p
  const float* Whhc;    // [1152,384]
  const float* Wihp;    // [1152,384]
  const float* bhhc;    // [1152]
  const float* bihp;    // [1152]
  const float* Wr0;     // [384,384]
  const float* Wr1;     // [384,384]
  const float* wk;      // [384] (enc only)
  const float* mask;    // enc: adj; dec: adjB (negated use)
  const float* smask;   // [8,96,96]
  float*       adjB;    // enc output
};

template<int ENC>
__global__ __launch_bounds__(256, 1)
void scan_kernel(ScanP p)
{
  const int tid  = threadIdx.x;
  const int b    = blockIdx.x >> 5;
  const int sl   = blockIdx.x & 31;
  const int j0   = sl * 12;
  const int team = tid >> 4, lane = tid & 15;

  __shared__ __align__(16) float stage[HID_];   // hn (P1) then M (P2)
  __shared__ float ws0[N_], ws1[N_], s_sm[N_], w_sm[N_];
  __shared__ float alpha[N_];
  __shared__ float dots[80];
  __shared__ float red4[4];
  __shared__ float sh_aknew;
  __shared__ float bufr0L[12][97];
  __shared__ float bufr1L[12][97];

  const int nd = ENC ? 25 : 24;

  // ---- hoist loop-invariant weight slices into registers ----
  const int rA0 = team, rA1 = team + 16;
  const float* wr0p = (rA0 < 12) ? p.Wr0 + (size_t)(j0 + rA0) * HID_
                                 : p.Wr1 + (size_t)(j0 + rA0 - 12) * HID_;
  const float* wr1p;
  if (rA1 < 24)      wr1p = p.Wr1 + (size_t)(j0 + rA1 - 12) * HID_;
  else if (rA1 < nd) wr1p = p.wk;
  else               wr1p = wr0p;               // dummy, result unused
  float4 wA0[6], wA1[6];
#pragma unroll
  for (int m = 0; m < 6; ++m) {
    wA0[m] = ((const float4*)wr0p)[lane + 16*m];
    wA1[m] = ((const float4*)wr1p)[lane + 16*m];
  }
  float4 wB[5][6];
#pragma unroll
  for (int u = 0; u < 5; ++u) {
    int rr = team + u * 16;
    if (rr < 72) {
      int jl = rr % 12, g = rr / 12;            // 0..2 Whhc r/z/n, 3..5 Wihp r/z/n
      const float4* w4 = (const float4*)((g < 3 ? p.Whhc : p.Wihp)
                           + (size_t)(j0 + jl + (g % 3) * HID_) * HID_);
#pragma unroll
      for (int m = 0; m < 6; ++m) wB[u][m] = w4[lane + 16*m];
    }
  }

  // Sentinel-gated bulk stage: 32 lanes poll one designated word per producer
  // slice, barrier, then one-shot bulk read with per-word sentinel recheck.
#define BULK_STAGE(SRC)                                                      \
  do {                                                                       \
    if (tid < 32) {                                                          \
      const float* f_ = (SRC) + tid * 12;                                    \
      while (__float_as_uint(atldf(f_)) == 0xFFFFFFFFu) {}                   \
    }                                                                        \
    __syncthreads();                                                         \
    {                                                                        \
      float v0 = atldf((SRC) + tid);                                         \
      while (__float_as_uint(v0) == 0xFFFFFFFFu) v0 = atldf((SRC) + tid);    \
      stage[tid] = v0;                                                       \
      if (tid < HID_ - 256) {                                                \
        float v1 = atldf((SRC) + 256 + tid);                                 \
        while (__float_as_uint(v1) == 0xFFFFFFFFu)                           \
          v1 = atldf((SRC) + 256 + tid);                                     \
        stage[256 + tid] = v1;                                               \
      }                                                                      \
    }                                                                        \
    __syncthreads();                                                         \
  } while (0)

  // ---- node 0 ----
  if (tid < 12) {
    int j = j0 + tid;
    const float* gi = p.GIc + (size_t)(b * N_) * GID_;
    const float* gh = p.GHp + (size_t)(b * N_) * GID_;
    float rc = sigf(gi[j] + p.bhhc[j]);
    float zc = sigf(gi[HID_ + j] + p.bhhc[HID_ + j]);
    float nc = tanhf(gi[2*HID_ + j] + rc * p.bhhc[2*HID_ + j]);
    float outc = (1.0f - zc) * nc;
    float rp = sigf(p.bihp[j] + gh[j]);
    float zp = sigf(p.bihp[HID_ + j] + gh[HID_ + j]);
    float np = tanhf(p.bihp[2*HID_ + j] + rp * gh[2*HID_ + j]);
    float x0 = p.Hl[(size_t)(b * N_) * CONC_ + j];
    float h0 = outc + (1.0f - zp) * np + zp * x0;
    p.bufC[(size_t)(b * N_) * CONC_ + j] = h0;
    atstf(&p.hnX[(size_t)(b * N_) * HID_ + j], h0);
  }

  for (int i = 1; i < N_; ++i) {
    // ---- prefetch step-i operands (hide under hn flight) ----
    float pf_gi0=0, pf_gi1=0, pf_gi2=0, pf_gh0=0, pf_gh1=0, pf_gh2=0, pf_q=0;
    if (tid < 12) {
      int j = j0 + tid;
      const float* gi = p.GIc + ((size_t)b * N_ + i) * GID_;
      const float* gh = p.GHp + ((size_t)b * N_ + i) * GID_;
      pf_gi0 = gi[j]; pf_gi1 = gi[HID_ + j]; pf_gi2 = gi[2*HID_ + j];
      pf_gh0 = gh[j]; pf_gh1 = gh[HID_ + j]; pf_gh2 = gh[2*HID_ + j];
      pf_q   = p.Hl[((size_t)b * N_ + i) * CONC_ + j];
    }
    float pf_mrow = 0.0f;
    if (tid < N_) {
      pf_mrow = p.mask[((size_t)b * N_ + i) * N_ + tid];
      s_sm[tid] = p.smask[((size_t)b * N_ + i) * N_ + tid];
    }

    // ---- wait + stage hn[i-1] ----
    const float* srcH = p.hnX + (size_t)(b * N_ + (i - 1)) * HID_;
    BULK_STAGE(srcH);
    const float4* st4 = (const float4*)stage;
    float4 hreg[6];
#pragma unroll
    for (int m = 0; m < 6; ++m) hreg[m] = st4[lane + 16*m];

    // ---- P1a: bufr columns + aknew ----
    {
      float a0 = 0.f, a1 = 0.f;
#pragma unroll
      for (int m = 0; m < 6; ++m) {
        a0 += dot4(wA0[m], hreg[m]);
        a1 += dot4(wA1[m], hreg[m]);
      }
#pragma unroll
      for (int mm = 8; mm; mm >>= 1) {
        a0 += __shfl_xor(a0, mm);
        a1 += __shfl_xor(a1, mm);
      }
      if (lane == 0) {
        if (rA0 < 12) bufr0L[rA0][i - 1] = a0;
        else          bufr1L[rA0 - 12][i - 1] = a0;
        if (rA1 < 24)      bufr1L[rA1 - 12][i - 1] = a1;
        else if (rA1 < nd) sh_aknew = a1;
      }
    }
    __syncthreads();

    // ---- P1b: attention weights, pre-scaled by s ----
    if (ENC) {
      if (tid == 0) alpha[i - 1] = sh_aknew;   // no reader of [i-1] this step
      float av = -3.0e38f;
      if (tid < i) {
        float ak = (tid == i - 1) ? sh_aknew : alpha[tid];
        av = ak - (1.0f - pf_mrow) * 1e30f;
      }
      float v = av;
#pragma unroll
      for (int m = 32; m; m >>= 1) v = fmaxf(v, __shfl_xor(v, m));
      if ((tid & 63) == 0) red4[tid >> 6] = v;
      __syncthreads();
      float mx = fmaxf(fmaxf(red4[0], red4[1]), fmaxf(red4[2], red4[3]));
      __syncthreads();
      float e = (tid < i) ? expf(av - mx) : 0.0f;
      v = e;
#pragma unroll
      for (int m = 32; m; m >>= 1) v += __shfl_xor(v, m);
      if ((tid & 63) == 0) red4[tid >> 6] = v;
      __syncthreads();
      float ssum = red4[0] + red4[1] + red4[2] + red4[3];
      if (tid < N_) {
        float w = (tid < i) ? e / ssum : 0.0f;
        w_sm[tid] = w;
        float sv = s_sm[tid];
        ws0[tid] = w * sv;
        ws1[tid] = w - w * sv;
      }
      __syncthreads();
      if (sl == 0 && tid < N_)
        p.adjB[((size_t)b * N_ + i) * N_ + tid] = w_sm[tid];
    } else {
      if (tid < N_) {
        float w = (tid < i) ? -pf_mrow : 0.0f;
        float sv = s_sm[tid];
        ws0[tid] = w * sv;
        ws1[tid] = w - w * sv;
      }
      __syncthreads();
    }

    // ---- P1c: M[slice] -> publish immediately ----
    if (team < 12) {
      float acc = 0.f;
      for (int n = lane; n < i; n += 16)
        acc = fmaf(ws0[n], bufr0L[team][n], fmaf(ws1[n], bufr1L[team][n], acc));
#pragma unroll
      for (int mm = 8; mm; mm >>= 1) acc += __shfl_xor(acc, mm);
      if (lane == 0) atstf(&p.MX[((size_t)b * N_ + i) * HID_ + j0 + team], acc);
    }

    // ---- wait + stage M[i] ----
    const float* srcM = p.MX + (size_t)(b * N_ + i) * HID_;
    BULK_STAGE(srcM);
    float4 mreg[6];
#pragma unroll
    for (int m = 0; m < 6; ++m) mreg[m] = st4[lane + 16*m];

    // ---- P2: gate dots from registers ----
#pragma unroll
    for (int u = 0; u < 5; ++u) {
      int rr = team + u * 16;
      if (rr < 72) {
        float acc = 0.f;
#pragma unroll
        for (int m = 0; m < 6; ++m) acc += dot4(wB[u][m], mreg[m]);
#pragma unroll
        for (int mm = 8; mm; mm >>= 1) acc += __shfl_xor(acc, mm);
        if (lane == 0) dots[rr] = acc;
      }
    }
    __syncthreads();
    if (tid < 12) {
      int j = j0 + tid;
      float Mj = stage[j];
      float rc = sigf(pf_gi0 + dots[tid] + p.bhhc[j]);
      float zc = sigf(pf_gi1 + dots[12 + tid] + p.bhhc[HID_ + j]);
      float nc = tanhf(pf_gi2 + rc * (dots[24 + tid] + p.bhhc[2*HID_ + j]));
      float outc = (1.0f - zc) * nc + zc * Mj;
      float rp = sigf(dots[36 + tid] + p.bihp[j] + pf_gh0);
      float zp = sigf(dots[48 + tid] + p.bihp[HID_ + j] + pf_gh1);
      float np = tanhf(dots[60 + tid] + p.bihp[2*HID_ + j] + rp * pf_gh2);
      float hv = outc + (1.0f - zp) * np + zp * pf_q;
      p.bufC[((size_t)b * N_ + i) * CONC_ + j] = hv;
      atstf(&p.hnX[((size_t)b * N_ + i) * HID_ + j], hv);
    }
    // next iteration's BULK_STAGE barrier protects stage[] reuse
  }
#undef BULK_STAGE
}

// ---------------- feature_map = I - adjB2 (row 0 implicit 0) ----------------
__global__ __launch_bounds__(256)
void fmap_kernel(const float* __restrict__ adjB2, float* __restrict__ out)
{
  int idx = blockIdx.x * 256 + threadIdx.x;
  if (idx < B_ * N_ * N_) {
    int j = idx % N_;
    int i = (idx / N_) % N_;
    float a = (i == 0) ? 0.0f : adjB2[idx];
    out[idx] = ((i == j) ? 1.0f : 0.0f) - a;
  }
}

// ---------------- orchestration ----------------
extern "C" void kernel_launch(void* const* d_in, const int* in_sizes, int n_in,
                              void* d_out, int out_size, void* d_ws, size_t ws_size,
                              hipStream_t stream)
{
  (void)in_sizes; (void)n_in; (void)out_size; (void)ws_size;
  const float* features     = (const float*)d_in[0];
  const float* adj          = (const float*)d_in[1];
  const float* s_mask       = (const float*)d_in[2];
  const float* enc_fc1_W    = (const float*)d_in[5];
  const float* enc_fc1_b    = (const float*)d_in[6];
  const float* enc_gat_w    = (const float*)d_in[7];
  const float* enc_Wr0      = (const float*)d_in[9];
  const float* enc_Wr1      = (const float*)d_in[10];
  const float* enc_gruc_Wih = (const float*)d_in[11];
  const float* enc_gruc_Whh = (const float*)d_in[12];
  const float* enc_gruc_bih = (const float*)d_in[13];
  const float* enc_gruc_bhh = (const float*)d_in[14];
  const float* enc_grup_Wih = (const float*)d_in[15];
  const float* enc_grup_Whh = (const float*)d_in[16];
  const float* enc_grup_bih = (const float*)d_in[17];
  const float* enc_grup_bhh = (const float*)d_in[18];
  const float* enc_mlp_W0   = (const float*)d_in[19];
  const float* enc_mlp_b0   = (const float*)d_in[20];
  const float* enc_mlp_W1   = (const float*)d_in[21];
  const float* enc_mlp_b1   = (const float*)d_in[22];
  const float* dec_fc1_W    = (const float*)d_in[23];
  const float* dec_fc1_b    = (const float*)d_in[24];
  const float* dec_Wr0      = (const float*)d_in[25];
  const float* dec_Wr1      = (const float*)d_in[26];
  const float* dec_gruc_Wih = (const float*)d_in[27];
  const float* dec_gruc_Whh = (const float*)d_in[28];
  const float* dec_gruc_bih = (const float*)d_in[29];
  const float* dec_gruc_bhh = (const float*)d_in[30];
  const float* dec_grup_Wih = (const float*)d_in[31];
  const float* dec_grup_Whh = (const float*)d_in[32];
  const float* dec_grup_bih = (const float*)d_in[33];
  const float* dec_grup_bhh = (const float*)d_in[34];
  const float* dec_mlp_W0   = (const float*)d_in[35];
  const float* dec_mlp_b0   = (const float*)d_in[36];
  const float* dec_mlp_W1   = (const float*)d_in[37];
  const float* dec_mlp_b1   = (const float*)d_in[38];

  float* ws = (float*)d_ws;
  size_t o = 0;
  float* Hse   = ws + o; o += (size_t)B_ * N_ * CONC_;
  float* Hsd   = ws + o; o += (size_t)B_ * N_ * CONC_;
  float* GIc   = ws + o; o += (size_t)B_ * N_ * GID_;
  float* GHp   = ws + o; o += (size_t)B_ * N_ * GID_;
  float* adjB1 = ws + o; o += (size_t)B_ * N_ * N_;
  float* adjB2 = ws + o; o += (size_t)B_ * N_ * N_;
  float* fU    = ws + o; o += (size_t)B_ * N_ * CODE_;
  float* Tmp   = ws + o; o += (size_t)B_ * N_ * HID_;
  float* hnX   = ws + o; o += (size_t)B_ * N_ * HID_;
  float* MX    = ws + o; o += (size_t)B_ * N_ * HID_;
  const size_t xch_bytes = (size_t)2 * B_ * N_ * HID_ * sizeof(float);

  const dim3 blk(256);
  float* logits = (float*)d_out;
  float* fmap   = (float*)d_out + (size_t)B_ * N_ * FEAT_;

  // encoder fc1
  gemm_bias<1><<<dim3(6, 12), blk, 0, stream>>>(features, EMB_, enc_fc1_W, enc_fc1_b,
                                                Hse, CONC_, EMB_);
  // encoder scans
  for (int l = 0; l < 2; ++l) {
    const float* Hl = Hse + l * HID_;
    gemm_bias<0><<<dim3(18, 12), blk, 0, stream>>>(Hl, CONC_,
        enc_gruc_Wih + (size_t)l * GID_ * HID_, enc_gruc_bih + l * GID_, GIc, GID_, HID_);
    gemm_bias<0><<<dim3(18, 12), blk, 0, stream>>>(Hl, CONC_,
        enc_grup_Whh + (size_t)l * GID_ * HID_, enc_grup_bhh + l * GID_, GHp, GID_, HID_);
    hipMemsetAsync(hnX, 0xFF, xch_bytes, stream);   // sentinel-fill hnX+MX
    ScanP p;
    p.Hl = Hl; p.bufC = Hse + (l + 1) * HID_;
    p.hnX = hnX; p.MX = MX;
    p.GIc = GIc; p.GHp = GHp;
    p.Whhc = enc_gruc_Whh + (size_t)l * GID_ * HID_;
    p.Wihp = enc_grup_Wih + (size_t)l * GID_ * HID_;
    p.bhhc = enc_gruc_bhh + l * GID_;
    p.bihp = enc_grup_bih + l * GID_;
    p.Wr0 = enc_Wr0 + (size_t)l * HID_ * HID_;
    p.Wr1 = enc_Wr1 + (size_t)l * HID_ * HID_;
    p.wk = enc_gat_w + l * 2 * HID_ + HID_;
    p.mask = adj; p.smask = s_mask;
    p.adjB = (l == 0) ? adjB1 : adjB2;
    scan_kernel<1><<<dim3(256), blk, 0, stream>>>(p);
  }
  // encoder MLP -> fU
  gemm_bias<1><<<dim3(6, 12), blk, 0, stream>>>(Hse, CONC_, enc_mlp_W0, enc_mlp_b0,
                                                Tmp, HID_, CONC_);
  gemm_bias<0><<<dim3(3, 12), blk, 0, stream>>>(Tmp, HID_, enc_mlp_W1, enc_mlp_b1,
                                                fU, CODE_, HID_);
  // decoder fc1
  gemm_bias<1><<<dim3(6, 12), blk, 0, stream>>>(fU, CODE_, dec_fc1_W, dec_fc1_b,
                                                Hsd, CONC_, CODE_);
  // decoder scans
  for (int l = 0; l < 2; ++l) {
    const float* Hl = Hsd + l * HID_;
    gemm_bias<0><<<dim3(18, 12), blk, 0, stream>>>(Hl, CONC_,
        dec_gruc_Wih + (size_t)l * GID_ * HID_, dec_gruc_bih + l * GID_, GIc, GID_, HID_);
    gemm_bias<0><<<dim3(18, 12), blk, 0, stream>>>(Hl, CONC_,
        dec_grup_Whh + (size_t)l * GID_ * HID_, dec_grup_bhh + l * GID_, GHp, GID_, HID_);
    hipMemsetAsync(hnX, 0xFF, xch_bytes, stream);
    ScanP p;
    p.Hl = Hl; p.bufC = Hsd + (l + 1) * HID_;
    p.hnX = hnX; p.MX = MX;
    p.GIc = GIc; p.GHp = GHp;
    p.Whhc = dec_gruc_Whh + (size_t)l * GID_ * HID_;
    p.Wihp = dec_grup_Wih + (size_t)l * GID_ * HID_;
    p.bhhc = dec_gruc_bhh + l * GID_;
    p.bihp = dec_grup_bih + l * GID_;
    p.Wr0 = dec_Wr0 + (size_t)l * HID_ * HID_;
    p.Wr1 = dec_Wr1 + (size_t)l * HID_ * HID_;
    p.wk = nullptr;
    p.mask = (l == 0) ? adjB1 : adjB2;   // w[n] = -adjB[b,i,n] for n<i
    p.smask = s_mask;
    p.adjB = nullptr;
    scan_kernel<0><<<dim3(256), blk, 0, stream>>>(p);
  }
  // decoder MLP -> logits
  gemm_bias<1><<<dim3(6, 12), blk, 0, stream>>>(Hsd, CONC_, dec_mlp_W0, dec_mlp_b0,
                                                Tmp, HID_, CONC_);
  gemm_bias<0><<<dim3(12, 12), blk, 0, stream>>>(Tmp, HID_, dec_mlp_W1, dec_mlp_b1,
                                                 logits, FEAT_, HID_);
  // feature_map
  fmap_kernel<<<dim3((B_ * N_ * N_ + 255) / 256), blk, 0, stream>>>(adjB2, fmap);
}